// Round 5
// baseline (117.326 us; speedup 1.0000x reference)
//
#include <hip/hip_runtime.h>
#include <hip/hip_bf16.h>
#include <math.h>

#define B_ROWS 4096
#define N_ROWS 8192
#define D 128
#define INV_T 2.0f
#define EXP2_SCALE 2.8853900817779268f  // INV_T * log2(e): exp(c*2) = exp2(c*EXP2_SCALE)
#define NT 64            // 64 row-tiles of 128
#define NBLK 2080        // NT*(NT+1)/2 upper-triangular tile pairs
#define NSLOT 128        // contribution slots per row (64 tiles x 2 waves)

typedef __attribute__((ext_vector_type(8))) short bf16x8;
typedef __attribute__((ext_vector_type(4))) float f32x4;

// ---------------- Kernel 1: L2-normalize rows -> bf16 Z ----------------
__global__ __launch_bounds__(256) void normalize_kernel(
    const float* __restrict__ z_i, const float* __restrict__ z_j,
    ushort* __restrict__ Z) {
  const int wave = threadIdx.x >> 6;
  const int lane = threadIdx.x & 63;
  const int row = blockIdx.x * 4 + wave;
  const float* src = (row < B_ROWS) ? (z_i + (size_t)row * D)
                                    : (z_j + (size_t)(row - B_ROWS) * D);
  float2 v = *(const float2*)(src + lane * 2);
  float ss = v.x * v.x + v.y * v.y;
#pragma unroll
  for (int off = 32; off > 0; off >>= 1) ss += __shfl_xor(ss, off);
  float scale = 1.0f / fmaxf(sqrtf(ss), 1e-12f);
  __hip_bfloat16 h0 = __float2bfloat16(v.x * scale);
  __hip_bfloat16 h1 = __float2bfloat16(v.y * scale);
  ushort2 o;
  o.x = *(ushort*)&h0;
  o.y = *(ushort*)&h1;
  *(ushort2*)(Z + (size_t)row * D + lane * 2) = o;
}

// ---------------- Kernel 2: symmetric MFMA exp-rowsum, NO LDS, NO barriers ----------------
// One block per tile-pair (I,J), J>=I. 4 independent waves (wy,wx); each computes a
// 64x64 subtile. Fragments come STRAIGHT from global: Z is 2 MB (L2-resident per
// XCD) and each bf16x8 fragment load is 100% line-efficient (64 lanes read 16 rows
// x one full 64B line). No LDS => no barriers, no staging register burst, and
// occupancy is VGPR-bound only: launch_bounds(256,4) => 128 VGPR cap, 16 waves/CU.
// Register budget: a[4][4]=64 + b[4]=16 + c=4 + rowsum=16 + colsum+addr ~15 => ~115.
// Partials slots: stripe I row-sums from (I,J) at slot 2J+wx; col-sums from (K,I)
// at slot 2K+wy => 128 slots/row, each written exactly once. No atomics.
__global__ __launch_bounds__(256, 4) void sim_kernel(
    const ushort* __restrict__ Z, float* __restrict__ partials,
    float* __restrict__ pos_buf) {
  // XCD-aware bijective swizzle (NBLK % 8 == 0)
  int idx = (int)(blockIdx.x % 8) * (NBLK / 8) + (int)(blockIdx.x / 8);
  // decode upper-triangular pair: base(I) = I*NT - I*(I-1)/2
  int I = (int)(64.5f - sqrtf(64.5f * 64.5f - 2.0f * (float)idx));
  if (I < 0) I = 0;
  if (I > NT - 1) I = NT - 1;
  while ((I + 1) * NT - ((I + 1) * I) / 2 <= idx) ++I;
  while (I * NT - (I * (I - 1)) / 2 > idx) --I;
  const int J = I + (idx - (I * NT - (I * (I - 1)) / 2));
  const int rI = I * 128, rJ = J * 128;
  const bool DIAG = (I == J);
  const bool POS = (J == I + 32);  // gi^gj == B_ROWS happens only here

  const int t = threadIdx.x;
  const int lane = t & 63;
  const int w = t >> 6;
  const int wy = w >> 1, wx = w & 1;
  const int l15 = lane & 15;
  const int l4 = lane >> 4;  // 0..3

  // A fragments: wave's 64 rows x K=128, resident in registers for the block.
  bf16x8 a[4][4];  // [row-subtile][k-subtile]
  const int arow = rI + wy * 64 + l15;
#pragma unroll
  for (int rs = 0; rs < 4; ++rs)
#pragma unroll
    for (int ks = 0; ks < 4; ++ks)
      a[rs][ks] = *(const bf16x8*)(Z + (size_t)(arow + rs * 16) * D + ks * 32 + l4 * 8);

  float rowsum[4][4];
#pragma unroll
  for (int rs = 0; rs < 4; ++rs)
#pragma unroll
    for (int r = 0; r < 4; ++r) rowsum[rs][r] = 0.f;
  float colsum[4] = {0.f, 0.f, 0.f, 0.f};

#pragma unroll
  for (int cs = 0; cs < 4; ++cs) {
    // B fragments for this 16-col subtile (4 K-subtiles), straight from L2.
    bf16x8 b[4];
    const int bcol = rJ + wx * 64 + cs * 16 + l15;
#pragma unroll
    for (int ks = 0; ks < 4; ++ks)
      b[ks] = *(const bf16x8*)(Z + (size_t)bcol * D + ks * 32 + l4 * 8);

    const int bt = wx * 64 + cs * 16 + l15;  // tile-local col of this lane
    float cp = 0.f;
    // ONE c fragment live at a time: epilogue immediately after each rs.
#pragma unroll
    for (int rs = 0; rs < 4; ++rs) {
      f32x4 c = (f32x4){0.f, 0.f, 0.f, 0.f};
#pragma unroll
      for (int ks = 0; ks < 4; ++ks)
        c = __builtin_amdgcn_mfma_f32_16x16x32_bf16(a[rs][ks], b[ks], c, 0, 0, 0);

      if (!DIAG && !POS) {
        // hot path (2016/2080 blocks): no masks
#pragma unroll
        for (int r = 0; r < 4; ++r) {
          float e = __builtin_amdgcn_exp2f(c[r] * EXP2_SCALE);
          rowsum[rs][r] += e;
          cp += e;
        }
      } else if (DIAG) {
#pragma unroll
        for (int r = 0; r < 4; ++r) {
          const int at = wy * 64 + rs * 16 + l4 * 4 + r;
          float e = __builtin_amdgcn_exp2f(c[r] * EXP2_SCALE);
          rowsum[rs][r] += (at != bt) ? e : 0.f;  // exact diagonal mask
          // diagonal tile contributes row-sums only (computed in full)
        }
      } else {  // POS tile (J == I+32): tile diagonal holds the positive pairs
#pragma unroll
        for (int r = 0; r < 4; ++r) {
          const int at = wy * 64 + rs * 16 + l4 * 4 + r;
          float s = c[r] * INV_T;
          float e = __builtin_amdgcn_exp2f(c[r] * EXP2_SCALE);
          if (at == bt) {
            pos_buf[rI + at] = s;   // row gi, positive col gj
            pos_buf[rJ + at] = s;   // mirror row gj (same value by symmetry)
          }
          rowsum[rs][r] += e;
          cp += e;
        }
      }
    }
    colsum[cs] = cp;
  }

  // Row sums: butterfly across the 16 column-lanes, store to slot 2J+wx.
#pragma unroll
  for (int rs = 0; rs < 4; ++rs)
#pragma unroll
    for (int r = 0; r < 4; ++r) {
      float v = rowsum[rs][r];
      v += __shfl_xor(v, 1);
      v += __shfl_xor(v, 2);
      v += __shfl_xor(v, 4);
      v += __shfl_xor(v, 8);
      if (l15 == 0)
        partials[(size_t)(2 * J + wx) * N_ROWS + rI + wy * 64 + rs * 16 + l4 * 4 + r] = v;
    }
  // Col sums (symmetry credit to J rows): reduce across row-lane-groups, slot 2I+wy.
  if (!DIAG) {
#pragma unroll
    for (int cs = 0; cs < 4; ++cs) {
      float v = colsum[cs];
      v += __shfl_xor(v, 16);
      v += __shfl_xor(v, 32);
      if (l4 == 0)
        partials[(size_t)(2 * I + wy) * N_ROWS + rJ + wx * 64 + cs * 16 + l15] = v;
    }
  }
}

// ---------------- Kernel 3: per-row term + block partial sums ----------------
__global__ __launch_bounds__(256) void reduce1_kernel(
    const float* __restrict__ partials, const float* __restrict__ pos_buf,
    float* __restrict__ loss_part) {
  const int row = blockIdx.x * 256 + threadIdx.x;
  float tot = 0.f;
#pragma unroll 8
  for (int s = 0; s < NSLOT; ++s) tot += partials[(size_t)s * N_ROWS + row];
  float term = logf(tot) - pos_buf[row];
#pragma unroll
  for (int off = 32; off > 0; off >>= 1) term += __shfl_xor(term, off);
  __shared__ float wsum[4];
  if ((threadIdx.x & 63) == 0) wsum[threadIdx.x >> 6] = term;
  __syncthreads();
  if (threadIdx.x == 0)
    loss_part[blockIdx.x] = wsum[0] + wsum[1] + wsum[2] + wsum[3];
}

// ---------------- Kernel 4: final 32 -> 1 ----------------
__global__ __launch_bounds__(64) void reduce2_kernel(
    const float* __restrict__ loss_part, float* __restrict__ out) {
  float v = (threadIdx.x < 32) ? loss_part[threadIdx.x] : 0.f;
#pragma unroll
  for (int off = 32; off > 0; off >>= 1) v += __shfl_xor(v, off);
  if (threadIdx.x == 0) out[0] = v / (float)N_ROWS;
}

extern "C" void kernel_launch(void* const* d_in, const int* in_sizes, int n_in,
                              void* d_out, int out_size, void* d_ws, size_t ws_size,
                              hipStream_t stream) {
  const float* z_i = (const float*)d_in[0];
  const float* z_j = (const float*)d_in[1];
  float* out = (float*)d_out;

  ushort* Z = (ushort*)d_ws;                                        // 2 MB
  float* partials = (float*)((char*)d_ws + (size_t)N_ROWS * D * sizeof(ushort));
  float* pos_buf = partials + (size_t)NSLOT * N_ROWS;               // after 4 MB
  float* loss_part = pos_buf + N_ROWS;                              // 32 KB after

  hipLaunchKernelGGL(normalize_kernel, dim3(N_ROWS / 4), dim3(256), 0, stream,
                     z_i, z_j, Z);
  hipLaunchKernelGGL(sim_kernel, dim3(NBLK), dim3(256), 0, stream, Z, partials,
                     pos_buf);
  hipLaunchKernelGGL(reduce1_kernel, dim3(N_ROWS / 256), dim3(256), 0, stream,
                     partials, pos_buf, loss_part);
  hipLaunchKernelGGL(reduce2_kernel, dim3(1), dim3(64), 0, stream, loss_part,
                     out);
}

// Round 6
// 93.857 us; speedup vs baseline: 1.2501x; 1.2501x over previous
//
#include <hip/hip_runtime.h>
#include <hip/hip_bf16.h>
#include <math.h>

#define B_ROWS 4096
#define N_ROWS 8192
#define D 128
#define INV_T 2.0f
#define EXP2_SCALE 2.8853900817779268f  // INV_T * log2(e): exp(c*2) = exp2(c*EXP2_SCALE)
#define NT 64            // 64 row-tiles of 128
#define NBLK 2080        // NT*(NT+1)/2 upper-triangular tile pairs
#define NSLOT 128        // contribution slots per row (64 tiles x 2 waves)

#define AS1 __attribute__((address_space(1)))
#define AS3 __attribute__((address_space(3)))

typedef __attribute__((ext_vector_type(8))) short bf16x8;
typedef __attribute__((ext_vector_type(4))) float f32x4;

// ---------------- Kernel 1: L2-normalize rows -> bf16 Z ----------------
__global__ __launch_bounds__(256) void normalize_kernel(
    const float* __restrict__ z_i, const float* __restrict__ z_j,
    ushort* __restrict__ Z) {
  const int wave = threadIdx.x >> 6;
  const int lane = threadIdx.x & 63;
  const int row = blockIdx.x * 4 + wave;
  const float* src = (row < B_ROWS) ? (z_i + (size_t)row * D)
                                    : (z_j + (size_t)(row - B_ROWS) * D);
  float2 v = *(const float2*)(src + lane * 2);
  float ss = v.x * v.x + v.y * v.y;
#pragma unroll
  for (int off = 32; off > 0; off >>= 1) ss += __shfl_xor(ss, off);
  float scale = 1.0f / fmaxf(sqrtf(ss), 1e-12f);
  __hip_bfloat16 h0 = __float2bfloat16(v.x * scale);
  __hip_bfloat16 h1 = __float2bfloat16(v.y * scale);
  ushort2 o;
  o.x = *(ushort*)&h0;
  o.y = *(ushort*)&h1;
  *(ushort2*)(Z + (size_t)row * D + lane * 2) = o;
}

// ---------------- Kernel 2: symmetric MFMA exp-rowsum ----------------
// One block per tile-pair (I,J), J>=I; 4 waves (wy,wx), each a 64x64 subtile.
// KEY: occupancy is LDS-bound (64KB/block => 2 blocks/CU = 2 waves/EU), so
// amdgpu_waves_per_eu(2,2) gives the allocator the full 256-VGPR budget =>
// zero spill (r5 counters: 64 VGPRs + 37MB scratch writes was the bottleneck).
// Staging: global_load_lds (no staging VGPRs), linear LDS dest + PRE-SWIZZLED
// per-lane global source; reads use the same XOR ((row&7)<<4) so stride-256B
// ds_read_b128 is bank-conflict-free (verified 0 conflicts in r3).
// Partials slots: stripe I row-sums from (I,J) at slot 2J+wx; col-sums from
// (K,I) at slot 2K+wy => 128 slots/row, each written exactly once. No atomics.
__global__ __launch_bounds__(256)
__attribute__((amdgpu_waves_per_eu(2, 2))) void sim_kernel(
    const ushort* __restrict__ Z, float* __restrict__ partials,
    float* __restrict__ pos_buf) {
  __shared__ ushort ldsA[128 * 128];  // 32 KB, stripe I (swizzled content)
  __shared__ ushort ldsB[128 * 128];  // 32 KB, stripe J

  // XCD-aware bijective swizzle (NBLK % 8 == 0)
  int idx = (int)(blockIdx.x % 8) * (NBLK / 8) + (int)(blockIdx.x / 8);
  // decode upper-triangular pair: base(I) = I*NT - I*(I-1)/2
  int I = (int)(64.5f - sqrtf(64.5f * 64.5f - 2.0f * (float)idx));
  if (I < 0) I = 0;
  if (I > NT - 1) I = NT - 1;
  while ((I + 1) * NT - ((I + 1) * I) / 2 <= idx) ++I;
  while (I * NT - (I * (I - 1)) / 2 > idx) --I;
  const int J = I + (idx - (I * NT - (I * (I - 1)) / 2));
  const int rI = I * 128, rJ = J * 128;
  const bool DIAG = (I == J);
  const bool POS = (J == I + 32);  // gi^gj == B_ROWS happens only here

  const int t = threadIdx.x;
  const int lane = t & 63;
  const int w = t >> 6;
  const int wy = w >> 1, wx = w & 1;
  const int l15 = lane & 15;
  const int l4 = lane >> 4;  // 0..3

  // ---- Stage both stripes via global_load_lds: zero staging registers ----
  // Wave w covers stripe rows [w*32, w*32+32): 8 iters x (1KB A + 1KB B).
  // HW dest = uniform base + lane*16 (linear); source is pre-swizzled so that
  // LDS[row*256 + x] = Z[(stripe+row)*256 + (x ^ ((row&7)<<4))].
  {
    const int chunk = l15;       // 16B chunk within the row
    const int rlo = lane >> 4;   // 0..3: row within the 4-row group
#pragma unroll
    for (int i = 0; i < 8; ++i) {
      const int row = w * 32 + i * 4 + rlo;              // per-lane stripe row
      const int srcoff = (chunk * 16) ^ ((row & 7) << 4);  // swizzled source
      const char* srcA = (const char*)Z + (size_t)(rI + row) * 256 + srcoff;
      const char* srcB = (const char*)Z + (size_t)(rJ + row) * 256 + srcoff;
      char* dstA = (char*)ldsA + (size_t)(w * 32 + i * 4) * 256;  // uniform
      char* dstB = (char*)ldsB + (size_t)(w * 32 + i * 4) * 256;
      __builtin_amdgcn_global_load_lds((AS1 const unsigned int*)srcA,
                                       (AS3 unsigned int*)dstA, 16, 0, 0);
      __builtin_amdgcn_global_load_lds((AS1 const unsigned int*)srcB,
                                       (AS3 unsigned int*)dstB, 16, 0, 0);
    }
  }
  __syncthreads();  // compiler emits vmcnt(0) before s_barrier

  // ---- A fragments from LDS: resident for the whole block (64 VGPR) ----
  bf16x8 a[4][4];  // [row-subtile][k-subtile]
#pragma unroll
  for (int rs = 0; rs < 4; ++rs) {
    const int ar = wy * 64 + rs * 16 + l15;
    const int ro = ar * 256, sw = (ar & 7) << 4;
#pragma unroll
    for (int ks = 0; ks < 4; ++ks)
      a[rs][ks] = *(const bf16x8*)((const char*)ldsA + ro + ((ks * 64 + l4 * 16) ^ sw));
  }

  float rowsum[4][4];
#pragma unroll
  for (int rs = 0; rs < 4; ++rs)
#pragma unroll
    for (int r = 0; r < 4; ++r) rowsum[rs][r] = 0.f;
  float colsum[4] = {0.f, 0.f, 0.f, 0.f};

#pragma unroll
  for (int cs = 0; cs < 4; ++cs) {
    bf16x8 b[4];
    const int br = wx * 64 + cs * 16 + l15;
    const int bo = br * 256, bsw = (br & 7) << 4;
#pragma unroll
    for (int ks = 0; ks < 4; ++ks)
      b[ks] = *(const bf16x8*)((const char*)ldsB + bo + ((ks * 64 + l4 * 16) ^ bsw));

    const int bt = wx * 64 + cs * 16 + l15;  // tile-local col of this lane
    float cp = 0.f;
#pragma unroll
    for (int rs = 0; rs < 4; ++rs) {
      f32x4 c = (f32x4){0.f, 0.f, 0.f, 0.f};
#pragma unroll
      for (int ks = 0; ks < 4; ++ks)
        c = __builtin_amdgcn_mfma_f32_16x16x32_bf16(a[rs][ks], b[ks], c, 0, 0, 0);

      if (!DIAG && !POS) {
        // hot path (2016/2080 blocks): no masks
#pragma unroll
        for (int r = 0; r < 4; ++r) {
          float e = __builtin_amdgcn_exp2f(c[r] * EXP2_SCALE);
          rowsum[rs][r] += e;
          cp += e;
        }
      } else if (DIAG) {
#pragma unroll
        for (int r = 0; r < 4; ++r) {
          const int at = wy * 64 + rs * 16 + l4 * 4 + r;
          float e = __builtin_amdgcn_exp2f(c[r] * EXP2_SCALE);
          rowsum[rs][r] += (at != bt) ? e : 0.f;  // exact diagonal mask
          // diagonal tile contributes row-sums only (computed in full)
        }
      } else {  // POS tile (J == I+32): tile diagonal holds the positive pairs
#pragma unroll
        for (int r = 0; r < 4; ++r) {
          const int at = wy * 64 + rs * 16 + l4 * 4 + r;
          float s = c[r] * INV_T;
          float e = __builtin_amdgcn_exp2f(c[r] * EXP2_SCALE);
          if (at == bt) {
            pos_buf[rI + at] = s;   // row gi, positive col gj
            pos_buf[rJ + at] = s;   // mirror row gj (same value by symmetry)
          }
          rowsum[rs][r] += e;
          cp += e;
        }
      }
    }
    colsum[cs] = cp;

    // Col sums for this cs (symmetry credit to J rows): reduce across the
    // 4 row-lane-groups; lanes 0..15 store 16 contiguous floats (64B line).
    if (!DIAG) {
      float v = colsum[cs];
      v += __shfl_xor(v, 16);
      v += __shfl_xor(v, 32);
      if (l4 == 0)
        partials[(size_t)(2 * I + wy) * N_ROWS + rJ + wx * 64 + cs * 16 + l15] = v;
    }
  }

  // Row sums: butterfly across the 16 column-lanes, then float4 store by the
  // 4 lanes with l15==0 (64B line per rs) to slot 2J+wx.
#pragma unroll
  for (int rs = 0; rs < 4; ++rs) {
    f32x4 v4;
#pragma unroll
    for (int r = 0; r < 4; ++r) {
      float v = rowsum[rs][r];
      v += __shfl_xor(v, 1);
      v += __shfl_xor(v, 2);
      v += __shfl_xor(v, 4);
      v += __shfl_xor(v, 8);
      v4[r] = v;
    }
    if (l15 == 0)
      *(f32x4*)&partials[(size_t)(2 * J + wx) * N_ROWS + rI + wy * 64 + rs * 16 + l4 * 4] = v4;
  }
}

// ---------------- Kernel 3: per-row term + block partial sums ----------------
__global__ __launch_bounds__(256) void reduce1_kernel(
    const float* __restrict__ partials, const float* __restrict__ pos_buf,
    float* __restrict__ loss_part) {
  const int row = blockIdx.x * 256 + threadIdx.x;
  float tot = 0.f;
#pragma unroll 8
  for (int s = 0; s < NSLOT; ++s) tot += partials[(size_t)s * N_ROWS + row];
  float term = logf(tot) - pos_buf[row];
#pragma unroll
  for (int off = 32; off > 0; off >>= 1) term += __shfl_xor(term, off);
  __shared__ float wsum[4];
  if ((threadIdx.x & 63) == 0) wsum[threadIdx.x >> 6] = term;
  __syncthreads();
  if (threadIdx.x == 0)
    loss_part[blockIdx.x] = wsum[0] + wsum[1] + wsum[2] + wsum[3];
}

// ---------------- Kernel 4: final 32 -> 1 ----------------
__global__ __launch_bounds__(64) void reduce2_kernel(
    const float* __restrict__ loss_part, float* __restrict__ out) {
  float v = (threadIdx.x < 32) ? loss_part[threadIdx.x] : 0.f;
#pragma unroll
  for (int off = 32; off > 0; off >>= 1) v += __shfl_xor(v, off);
  if (threadIdx.x == 0) out[0] = v / (float)N_ROWS;
}

extern "C" void kernel_launch(void* const* d_in, const int* in_sizes, int n_in,
                              void* d_out, int out_size, void* d_ws, size_t ws_size,
                              hipStream_t stream) {
  const float* z_i = (const float*)d_in[0];
  const float* z_j = (const float*)d_in[1];
  float* out = (float*)d_out;

  ushort* Z = (ushort*)d_ws;                                        // 2 MB
  float* partials = (float*)((char*)d_ws + (size_t)N_ROWS * D * sizeof(ushort));
  float* pos_buf = partials + (size_t)NSLOT * N_ROWS;               // after 4 MB
  float* loss_part = pos_buf + N_ROWS;                              // 32 KB after

  hipLaunchKernelGGL(normalize_kernel, dim3(N_ROWS / 4), dim3(256), 0, stream,
                     z_i, z_j, Z);
  hipLaunchKernelGGL(sim_kernel, dim3(NBLK), dim3(256), 0, stream, Z, partials,
                     pos_buf);
  hipLaunchKernelGGL(reduce1_kernel, dim3(N_ROWS / 256), dim3(256), 0, stream,
                     partials, pos_buf, loss_part);
  hipLaunchKernelGGL(reduce2_kernel, dim3(1), dim3(64), 0, stream, loss_part,
                     out);
}